// Round 11
// baseline (410.647 us; speedup 1.0000x reference)
//
#include <hip/hip_runtime.h>
#include <math.h>

#define S_LEN 2048
#define DM 1024
#define NH 16
#define DK 64

typedef __attribute__((ext_vector_type(8))) short short8;
typedef __attribute__((ext_vector_type(4))) short short4v;
typedef __attribute__((ext_vector_type(4))) float f32x4;

__device__ __forceinline__ short f2bf(float f) {
  unsigned u = __builtin_bit_cast(unsigned, f);
  u = (u + 0x7FFFu + ((u >> 16) & 1u)) >> 16;
  return (short)u;
}

__device__ __forceinline__ void gld_lds16(const short* g, short* l) {
  __builtin_amdgcn_global_load_lds(
      (const __attribute__((address_space(1))) unsigned int*)g,
      (__attribute__((address_space(3))) unsigned int*)l, 16, 0, 0);
}

// ---------------- f32 -> bf16 convert (blockIdx.y selects tensor) ----------------
__global__ __launch_bounds__(256) void cvt_bf16(
    const float* __restrict__ s0, const float* __restrict__ s1,
    const float* __restrict__ s2, const float* __restrict__ s3,
    short* __restrict__ d0, short* __restrict__ d1,
    short* __restrict__ d2, short* __restrict__ d3, int n)
{
  const float* s; short* d;
  switch (blockIdx.y) {
    case 0:  s = s0; d = d0; break;
    case 1:  s = s1; d = d1; break;
    case 2:  s = s2; d = d2; break;
    default: s = s3; d = d3; break;
  }
  const int i = (blockIdx.x * 256 + threadIdx.x) * 8;
  if (i < n) {
    const float4 v0 = *(const float4*)&s[i];
    const float4 v1 = *(const float4*)&s[i + 4];
    short8 r = { f2bf(v0.x), f2bf(v0.y), f2bf(v0.z), f2bf(v0.w),
                 f2bf(v1.x), f2bf(v1.y), f2bf(v1.z), f2bf(v1.w) };
    *(short8*)&d[i] = r;
  }
}

// ---------------- fused 3-way projection GEMM (m97 staging) ----------------------
// z=0: Q -> (B,H,S,DK); z=1: K -> (B,H,S,DK); z=2: V -> (B,H,DK,S) transposed
// (z==2 uses an LDS-transpose epilogue for coalesced V^T writes)
__global__ __launch_bounds__(256) void proj3(
    const short* __restrict__ qb, const short* __restrict__ kb, const short* __restrict__ vb,
    const short* __restrict__ wqb, const short* __restrict__ wkb, const short* __restrict__ wvb,
    const float* __restrict__ biq, const float* __restrict__ bik, const float* __restrict__ biv,
    short* __restrict__ qhb, short* __restrict__ khb, short* __restrict__ vtb)
{
  __shared__ short SM[17408];          // As(4096) + Bs(4096) during K-loop; Ct[128][136] in z==2 epilogue
  short* As = SM;
  short* Bs = SM + 4096;

  const int z = blockIdx.z;
  const short* A; const short* B; const float* bias; short* o;
  if (z == 0)      { A = qb; B = wqb; bias = biq; o = qhb; }
  else if (z == 1) { A = kb; B = wkb; bias = bik; o = khb; }
  else             { A = vb; B = wvb; bias = biv; o = vtb; }

  const int tid = threadIdx.x;
  const int lane = tid & 63;
  const int wv = tid >> 6;
  const int grp = lane >> 4, lid = lane & 15;
  const int wr = wv >> 1, wc = wv & 1;
  const int bm = blockIdx.x, bn = blockIdx.y;

  f32x4 acc[4][4] = {};

  const int idx0 = tid, idx1 = 256 + tid;
  const int r0 = idx0 >> 2, c0 = (idx0 & 3) * 8;
  const int r1 = idx1 >> 2, c1 = (idx1 & 3) * 8;
  const short* a0 = &A[(size_t)(bm * 128 + r0) * DM + c0];
  const short* a1 = &A[(size_t)(bm * 128 + r1) * DM + c1];
  const short* b0 = &B[(size_t)(bn * 128 + r0) * DM + c0];
  const short* b1 = &B[(size_t)(bn * 128 + r1) * DM + c1];

  for (int ks = 0; ks < 32; ++ks) {
    __syncthreads();
    gld_lds16(a0 + ks * 32, &As[idx0 * 8]);
    gld_lds16(a1 + ks * 32, &As[idx1 * 8]);
    gld_lds16(b0 + ks * 32, &Bs[idx0 * 8]);
    gld_lds16(b1 + ks * 32, &Bs[idx1 * 8]);
    __syncthreads();
    short8 a[4], b[4];
    #pragma unroll
    for (int m = 0; m < 4; ++m) a[m] = *(const short8*)&As[(wr * 64 + m * 16 + lid) * 32 + grp * 8];
    #pragma unroll
    for (int n = 0; n < 4; ++n) b[n] = *(const short8*)&Bs[(wc * 64 + n * 16 + lid) * 32 + grp * 8];
    #pragma unroll
    for (int m = 0; m < 4; ++m)
      #pragma unroll
      for (int n = 0; n < 4; ++n)
        acc[m][n] = __builtin_amdgcn_mfma_f32_16x16x32_bf16(a[m], b[n], acc[m][n], 0, 0, 0);
  }

  if (z < 2) {
    #pragma unroll
    for (int n = 0; n < 4; ++n) {
      const int ng = bn * 128 + wc * 64 + n * 16 + lid;
      const float bvs = bias[ng];
      const int h = ng >> 6, d = ng & 63;
      #pragma unroll
      for (int m = 0; m < 4; ++m) {
        const int mg = bm * 128 + wr * 64 + m * 16 + grp * 4;
        const int bb = mg >> 11, s = mg & 2047;
        #pragma unroll
        for (int r = 0; r < 4; ++r)
          o[(((size_t)bb * NH + h) * S_LEN + s + r) * DK + d] = f2bf(acc[m][n][r] + bvs);
      }
    }
  } else {
    // LDS transpose: C^T tile (rows = ng/dhead, cols = s), then coalesced writes
    __syncthreads();   // K-loop LDS reads done before overwriting with Ct
    #pragma unroll
    for (int n = 0; n < 4; ++n) {
      const int ngl = wc * 64 + n * 16 + lid;
      const float bvs = bias[bn * 128 + ngl];
      #pragma unroll
      for (int m = 0; m < 4; ++m) {
        const int sl = wr * 64 + m * 16 + grp * 4;
        short4v c4 = { f2bf(acc[m][n][0] + bvs), f2bf(acc[m][n][1] + bvs),
                       f2bf(acc[m][n][2] + bvs), f2bf(acc[m][n][3] + bvs) };
        *(short4v*)&SM[ngl * 136 + sl] = c4;
      }
    }
    __syncthreads();
    const int bb = bm >> 4, s0 = (bm & 15) * 128;
    #pragma unroll
    for (int i = 0; i < 8; ++i) {
      const int id = tid + 256 * i;         // 0..2047
      const int row = id >> 4;              // 0..127
      const int c8 = (id & 15) * 8;         // 0..120
      const short8 vv = *(const short8*)&SM[row * 136 + c8];
      *(short8*)&o[((size_t)bb * 1024 + bn * 128 + row) * S_LEN + s0 + c8] = vv;
    }
  }
}

// ---------------- O-projection: C = A @ B^T + bias -> f32 [M,DM] (NT out) --------
__global__ __launch_bounds__(256) void gemm_o(
    const short* __restrict__ A, const short* __restrict__ B,
    const float* __restrict__ bias, float* __restrict__ of)
{
  __shared__ short As[128 * 32];
  __shared__ short Bs[128 * 32];
  const int tid = threadIdx.x;
  const int lane = tid & 63;
  const int wv = tid >> 6;
  const int grp = lane >> 4, lid = lane & 15;
  const int wr = wv >> 1, wc = wv & 1;
  const int bm = blockIdx.x, bn = blockIdx.y;

  f32x4 acc[4][4] = {};

  const int idx0 = tid, idx1 = 256 + tid;
  const int r0 = idx0 >> 2, c0 = (idx0 & 3) * 8;
  const int r1 = idx1 >> 2, c1 = (idx1 & 3) * 8;
  const short* a0 = &A[(size_t)(bm * 128 + r0) * DM + c0];
  const short* a1 = &A[(size_t)(bm * 128 + r1) * DM + c1];
  const short* b0 = &B[(size_t)(bn * 128 + r0) * DM + c0];
  const short* b1 = &B[(size_t)(bn * 128 + r1) * DM + c1];

  for (int ks = 0; ks < 32; ++ks) {
    __syncthreads();
    gld_lds16(a0 + ks * 32, &As[idx0 * 8]);
    gld_lds16(a1 + ks * 32, &As[idx1 * 8]);
    gld_lds16(b0 + ks * 32, &Bs[idx0 * 8]);
    gld_lds16(b1 + ks * 32, &Bs[idx1 * 8]);
    __syncthreads();
    short8 a[4], b[4];
    #pragma unroll
    for (int m = 0; m < 4; ++m) a[m] = *(const short8*)&As[(wr * 64 + m * 16 + lid) * 32 + grp * 8];
    #pragma unroll
    for (int n = 0; n < 4; ++n) b[n] = *(const short8*)&Bs[(wc * 64 + n * 16 + lid) * 32 + grp * 8];
    #pragma unroll
    for (int m = 0; m < 4; ++m)
      #pragma unroll
      for (int n = 0; n < 4; ++n)
        acc[m][n] = __builtin_amdgcn_mfma_f32_16x16x32_bf16(a[m], b[n], acc[m][n], 0, 0, 0);
  }

  #pragma unroll
  for (int n = 0; n < 4; ++n) {
    const int ng = bn * 128 + wc * 64 + n * 16 + lid;
    const float bvs = bias[ng];
    #pragma unroll
    for (int m = 0; m < 4; ++m) {
      const int mg = bm * 128 + wr * 64 + m * 16 + grp * 4;
      #pragma unroll
      for (int r = 0; r < 4; ++r)
        __builtin_nontemporal_store(acc[m][n][r] + bvs, &of[(size_t)(mg + r) * DM + ng]);
    }
  }
}

// ---------------- fused attention v9: BARRIER-FREE -------------------------------
// Wave-private K/V^T/Ps tiles (32-key steps): all LDS deps are intra-wave, DS ops
// execute in order per wave -> zero s_barrier. 2 independent waves per block,
// 24 KB LDS -> 6 blocks/CU -> 12 free-running waves/CU. Swapped QK^T, exp2 softmax,
// NT attn stores from Ps.
__global__ __launch_bounds__(128) void mha_attn9(
    const short* __restrict__ qh, const short* __restrict__ kh, const short* __restrict__ vt,
    float* __restrict__ attn, short* __restrict__ xb)
{
  __shared__ short Kt[2][32][72];   // per-wave K tile: 32 keys x 64 d
  __shared__ short Vt[2][64][40];   // per-wave V^T tile: 64 d x 32 keys
  __shared__ short Ps[2][32][40];   // per-wave P tile: 32 q x 32 keys (bf16)

  const int tid = threadIdx.x;
  const int lane = tid & 63, wv = tid >> 6, grp = lane >> 4, lid = lane & 15;

  // XCD swizzle: all 32 q-tiles of one bh on one XCD (K+V^T = 512KB L2-resident)
  const int nid = blockIdx.x;               // 0..2047
  const int x = nid & 7, jj = nid >> 3;     // jj 0..255
  const int bh = x + 8 * (jj >> 5);         // 0..63
  const int qt = jj & 31;                   // 0..31 (64-row tiles)

  const size_t baseQ = (size_t)bh * S_LEN * DK;
  const size_t baseV = (size_t)bh * DK * S_LEN;
  const float scale2 = 0.18033688f;   // (1/8) * log2(e)

  const short* Qb = qh + baseQ;
  const short* Kb = kh + baseQ;
  const short* Vb = vt + baseV;

  // per-wave staging decomposition (chunk id c = lane + 64*i, i<4)
  int trk[4], tck[4], trv[4], tcv[4];
  #pragma unroll
  for (int i = 0; i < 4; ++i) {
    const int c = lane + 64 * i;          // 0..255
    trk[i] = c >> 3;  tck[i] = (c & 7) * 8;   // K: 32 rows x 8 chunks
    trv[i] = c >> 2;  tcv[i] = (c & 3) * 8;   // V^T: 64 rows x 4 chunks
  }

  // Q fragments: direct global (16B/lane contiguous); used as mfma B-operand
  short8 aq[2][2];
  #pragma unroll
  for (int qb2 = 0; qb2 < 2; ++qb2)
    #pragma unroll
    for (int kf = 0; kf < 2; ++kf)
      aq[qb2][kf] = *(const short8*)&Qb[(size_t)(qt * 64 + wv * 32 + qb2 * 16 + lid) * DK + kf * 32 + grp * 8];

  float lsum[2] = {};

  // ---- pass 1: denominators; wave-private K tile, no barriers ----
  short8 kr[4];
  #pragma unroll
  for (int i = 0; i < 4; ++i) kr[i] = *(const short8*)&Kb[(size_t)trk[i] * DK + tck[i]];
  for (int kt = 0; kt < 64; ++kt) {
    #pragma unroll
    for (int i = 0; i < 4; ++i) *(short8*)&Kt[wv][trk[i]][tck[i]] = kr[i];
    if (kt < 63) {
      #pragma unroll
      for (int i = 0; i < 4; ++i)
        kr[i] = *(const short8*)&Kb[(size_t)((kt + 1) * 32 + trk[i]) * DK + tck[i]];
    }
    f32x4 sacc[2][2] = {};   // [key-block][q-block], C rows=key cols=q
    __builtin_amdgcn_s_setprio(1);
    #pragma unroll
    for (int kf = 0; kf < 2; ++kf) {
      short8 ak[2];
      #pragma unroll
      for (int kb2 = 0; kb2 < 2; ++kb2) ak[kb2] = *(const short8*)&Kt[wv][kb2 * 16 + lid][kf * 32 + grp * 8];
      #pragma unroll
      for (int kb2 = 0; kb2 < 2; ++kb2)
        #pragma unroll
        for (int qb2 = 0; qb2 < 2; ++qb2)
          sacc[kb2][qb2] = __builtin_amdgcn_mfma_f32_16x16x32_bf16(ak[kb2], aq[qb2][kf], sacc[kb2][qb2], 0, 0, 0);
    }
    __builtin_amdgcn_s_setprio(0);
    #pragma unroll
    for (int qb2 = 0; qb2 < 2; ++qb2)
      #pragma unroll
      for (int kb2 = 0; kb2 < 2; ++kb2)
        #pragma unroll
        for (int r = 0; r < 4; ++r)
          lsum[qb2] += __builtin_amdgcn_exp2f(sacc[kb2][qb2][r] * scale2);
  }

  float log2l[2];
  #pragma unroll
  for (int qb2 = 0; qb2 < 2; ++qb2) {
    float s = lsum[qb2];
    s += __shfl_xor(s, 16);
    s += __shfl_xor(s, 32);
    log2l[qb2] = __log2f(s);
  }

  f32x4 oacc[2][4] = {};
  float* attnB = attn + ((size_t)bh * S_LEN + qt * 64 + wv * 32) * S_LEN;

  // ---- pass 2: recompute scores (swapped), Ps, PV, attn NT store; no barriers ----
  short8 vr[4];
  #pragma unroll
  for (int i = 0; i < 4; ++i) {
    kr[i] = *(const short8*)&Kb[(size_t)trk[i] * DK + tck[i]];
    vr[i] = *(const short8*)&Vb[(size_t)trv[i] * S_LEN + tcv[i]];
  }
  for (int kt = 0; kt < 64; ++kt) {
    #pragma unroll
    for (int i = 0; i < 4; ++i) {
      *(short8*)&Kt[wv][trk[i]][tck[i]] = kr[i];
      *(short8*)&Vt[wv][trv[i]][tcv[i]] = vr[i];
    }
    if (kt < 63) {
      #pragma unroll
      for (int i = 0; i < 4; ++i) {
        kr[i] = *(const short8*)&Kb[(size_t)((kt + 1) * 32 + trk[i]) * DK + tck[i]];
        vr[i] = *(const short8*)&Vb[(size_t)trv[i] * S_LEN + (kt + 1) * 32 + tcv[i]];
      }
    }

    f32x4 sacc[2][2] = {};
    __builtin_amdgcn_s_setprio(1);
    #pragma unroll
    for (int kf = 0; kf < 2; ++kf) {
      short8 ak[2];
      #pragma unroll
      for (int kb2 = 0; kb2 < 2; ++kb2) ak[kb2] = *(const short8*)&Kt[wv][kb2 * 16 + lid][kf * 32 + grp * 8];
      #pragma unroll
      for (int kb2 = 0; kb2 < 2; ++kb2)
        #pragma unroll
        for (int qb2 = 0; qb2 < 2; ++qb2)
          sacc[kb2][qb2] = __builtin_amdgcn_mfma_f32_16x16x32_bf16(ak[kb2], aq[qb2][kf], sacc[kb2][qb2], 0, 0, 0);
    }
    __builtin_amdgcn_s_setprio(0);

    // softmax -> Ps (normalization folded into exp2 arg); vector b64 writes
    #pragma unroll
    for (int qb2 = 0; qb2 < 2; ++qb2) {
      const float nl = -log2l[qb2];
      #pragma unroll
      for (int kb2 = 0; kb2 < 2; ++kb2) {
        short4v p4;
        #pragma unroll
        for (int r = 0; r < 4; ++r)
          p4[r] = f2bf(__builtin_amdgcn_exp2f(__builtin_fmaf(sacc[kb2][qb2][r], scale2, nl)));
        *(short4v*)&Ps[wv][qb2 * 16 + lid][kb2 * 16 + grp * 4] = p4;
      }
    }

    // PV: K-dim = 32 keys (single MFMA K-chunk); intra-wave lgkm ordering
    __builtin_amdgcn_s_setprio(1);
    {
      short8 ap[2], bvv[4];
      #pragma unroll
      for (int mf = 0; mf < 2; ++mf) ap[mf] = *(const short8*)&Ps[wv][mf * 16 + lid][grp * 8];
      #pragma unroll
      for (int nf = 0; nf < 4; ++nf) bvv[nf] = *(const short8*)&Vt[wv][nf * 16 + lid][grp * 8];
      #pragma unroll
      for (int mf = 0; mf < 2; ++mf)
        #pragma unroll
        for (int nf = 0; nf < 4; ++nf)
          oacc[mf][nf] = __builtin_amdgcn_mfma_f32_16x16x32_bf16(ap[mf], bvv[nf], oacc[mf][nf], 0, 0, 0);
    }
    __builtin_amdgcn_s_setprio(0);

    // attn f32 store sourced from Ps (bf16->f32 via bit ops), f32x4 NT stores
    #pragma unroll
    for (int i = 0; i < 4; ++i) {
      const int c = lane + 64 * i;          // 0..255
      const int qrow = c >> 3;              // 0..31
      const int kc4 = (c & 7) * 4;          // 0..28
      const uint2 u = *(const uint2*)&Ps[wv][qrow][kc4];
      f32x4 f;
      f[0] = __builtin_bit_cast(float, u.x << 16);
      f[1] = __builtin_bit_cast(float, u.x & 0xffff0000u);
      f[2] = __builtin_bit_cast(float, u.y << 16);
      f[3] = __builtin_bit_cast(float, u.y & 0xffff0000u);
      __builtin_nontemporal_store(f, (f32x4*)&attnB[(size_t)qrow * S_LEN + kt * 32 + kc4]);
    }
  }

  // write attention output in (B,S,DM) bf16 layout for the O-projection
  const int b = bh >> 4, h = bh & 15;
  #pragma unroll
  for (int mf = 0; mf < 2; ++mf) {
    #pragma unroll
    for (int nf = 0; nf < 4; ++nf) {
      #pragma unroll
      for (int r = 0; r < 4; ++r) {
        const int s = qt * 64 + wv * 32 + mf * 16 + grp * 4 + r;
        const int d = nf * 16 + lid;
        xb[((size_t)b * S_LEN + s) * DM + h * DK + d] = f2bf(oacc[mf][nf][r]);
      }
    }
  }
}

// ================= fallback path kernels (small ws): round-2 structure ===========
template<int MODE>
__global__ __launch_bounds__(256) void mha_gemm(
    const float* __restrict__ Af, const short* __restrict__ Ab,
    const float* __restrict__ W, const float* __restrict__ bias,
    short* __restrict__ obf, float* __restrict__ of)
{
  __shared__ short As[128][40];
  __shared__ short Bs[128][40];
  const int tid = threadIdx.x;
  const int lane = tid & 63, wv = tid >> 6;
  const int grp = lane >> 4, lid = lane & 15;
  const int wr = wv >> 1, wc = wv & 1;
  const int bm = blockIdx.x, bn = blockIdx.y;

  f32x4 acc[4][4] = {};

  for (int ks = 0; ks < 32; ++ks) {
    __syncthreads();
    if (MODE == 0) {
      #pragma unroll
      for (int i = 0; i < 4; ++i) {
        const int c = tid + 256 * i;
        const int row = c >> 3, kc = c & 7;
        const float4 v = *(const float4*)&Af[(size_t)(bm * 128 + row) * DM + ks * 32 + kc * 4];
        short4v s4 = { f2bf(v.x), f2bf(v.y), f2bf(v.z), f2bf(v.w) };
        *(short4v*)&As[row][kc * 4] = s4;
      }
    } else {
      #pragma unroll
      for (int i = 0; i < 2; ++i) {
        const int c = tid + 256 * i;
        const int row = c >> 2, k8 = (c & 3) * 8;
        *(float4*)&As[row][k8] = *(const float4*)&Ab[(size_t)(bm * 128 + row) * DM + ks * 32 + k8];
      }
    }
    #pragma unroll
    for (int i = 0; i < 4; ++i) {
      const int c = tid + 256 * i;
      const int row = c >> 3, kc = c & 7;
      const float4 v = *(const float4*)&W[(size_t)(bn * 128 + row) * DM + ks * 32 + kc * 4];
      short4v s4 = { f2bf(v.x), f2bf(v.y), f2bf(v.z), f2bf(v.w) };
      *(short4v*)&Bs[row][kc * 4] = s4;
    }
    __syncthreads();
    short8 a[4], b[4];
    #pragma unroll
    for (int m = 0; m < 4; ++m) a[m] = *(const short8*)&As[wr * 64 + m * 16 + lid][grp * 8];
    #pragma unroll
    for (int n = 0; n < 4; ++n) b[n] = *(const short8*)&Bs[wc * 64 + n * 16 + lid][grp * 8];
    #pragma unroll
    for (int m = 0; m < 4; ++m)
      #pragma unroll
      for (int n = 0; n < 4; ++n)
        acc[m][n] = __builtin_amdgcn_mfma_f32_16x16x32_bf16(a[m], b[n], acc[m][n], 0, 0, 0);
  }

  #pragma unroll
  for (int n = 0; n < 4; ++n) {
    const int ng = bn * 128 + wc * 64 + n * 16 + lid;
    const float bvs = bias[ng];
    #pragma unroll
    for (int m = 0; m < 4; ++m) {
      const int mg = bm * 128 + wr * 64 + m * 16 + grp * 4;
      #pragma unroll
      for (int r = 0; r < 4; ++r) {
        const float val = acc[m][n][r] + bvs;
        const int mm = mg + r;
        if (MODE == 0) {
          const int bb = mm >> 11, s = mm & 2047, h = ng >> 6, d = ng & 63;
          obf[(((size_t)bb * NH + h) * S_LEN + s) * DK + d] = f2bf(val);
        } else {
          of[(size_t)mm * DM + ng] = val;
        }
      }
    }
  }
}

__global__ __launch_bounds__(256) void mha_attn_old(
    const short* __restrict__ qh, const short* __restrict__ kh, const short* __restrict__ vh,
    float* __restrict__ attn, short* __restrict__ xb)
{
  __shared__ short QP[128][72];
  __shared__ short Ks[64][72];
  __shared__ short VT[64][72];

  const int tid = threadIdx.x;
  const int lane = tid & 63, wv = tid >> 6, grp = lane >> 4, lid = lane & 15;
  const int qt = blockIdx.x, bh = blockIdx.y;
  const size_t base = (size_t)bh * S_LEN * DK;
  const float scale = 0.125f;

  #pragma unroll
  for (int i = 0; i < 4; ++i) {
    const int c = tid + 256 * i;
    const int row = c >> 3, k8 = (c & 7) * 8;
    *(float4*)&QP[row][k8] = *(const float4*)&qh[base + (size_t)(qt * 128 + row) * DK + k8];
  }
  __syncthreads();
  short8 aq[2][2];
  #pragma unroll
  for (int mf = 0; mf < 2; ++mf)
    #pragma unroll
    for (int kf = 0; kf < 2; ++kf)
      aq[mf][kf] = *(const short8*)&QP[wv * 32 + mf * 16 + lid][kf * 32 + grp * 8];

  float lsum[2][4] = {};

  for (int kt = 0; kt < 32; ++kt) {
    __syncthreads();
    #pragma unroll
    for (int i = 0; i < 2; ++i) {
      const int c = tid + 256 * i;
      const int row = c >> 3, k8 = (c & 7) * 8;
      *(float4*)&Ks[row][k8] = *(const float4*)&kh[base + (size_t)(kt * 64 + row) * DK + k8];
    }
    __syncthreads();
    f32x4 sacc[2][4] = {};
    #pragma unroll
    for (int kf = 0; kf < 2; ++kf) {
      short8 bk[4];
      #pragma unroll
      for (int nf = 0; nf < 4; ++nf) bk[nf] = *(const short8*)&Ks[nf * 16 + lid][kf * 32 + grp * 8];
      #pragma unroll
      for (int mf = 0; mf < 2; ++mf)
        #pragma unroll
        for (int nf = 0; nf < 4; ++nf)
          sacc[mf][nf] = __builtin_amdgcn_mfma_f32_16x16x32_bf16(aq[mf][kf], bk[nf], sacc[mf][nf], 0, 0, 0);
    }
    #pragma unroll
    for (int mf = 0; mf < 2; ++mf)
      #pragma unroll
      for (int r = 0; r < 4; ++r)
        #pragma unroll
        for (int nf = 0; nf < 4; ++nf)
          lsum[mf][r] += __expf(sacc[mf][nf][r] * scale);
  }

  float rl[2][4];
  #pragma unroll
  for (int mf = 0; mf < 2; ++mf)
    #pragma unroll
    for (int r = 0; r < 4; ++r) {
      float s = lsum[mf][r];
      #pragma unroll
      for (int off = 8; off >= 1; off >>= 1) s += __shfl_xor(s, off, 16);
      rl[mf][r] = 1.f / s;
    }

  f32x4 oacc[2][4] = {};

  for (int kt = 0; kt < 32; ++kt) {
    __syncthreads();
    #pragma unroll
    for (int i = 0; i < 2; ++i) {
      const int c = tid + 256 * i;
      const int row = c >> 3, k8 = (c & 7) * 8;
      *(float4*)&Ks[row][k8] = *(const float4*)&kh[base + (size_t)(kt * 64 + row) * DK + k8];
    }
    #pragma unroll
    for (int i = 0; i < 2; ++i) {
      const int key = tid & 63;
      const int d0 = ((tid >> 6) << 3) + i * 32;
      const float4 v = *(const float4*)&vh[base + (size_t)(kt * 64 + key) * DK + d0];
      const short8 sv = __builtin_bit_cast(short8, v);
      #pragma unroll
      for (int jj = 0; jj < 8; ++jj) VT[d0 + jj][key] = sv[jj];
    }
    __syncthreads();
    f32x4 sacc[2][4] = {};
    #pragma unroll
    for (int kf = 0; kf < 2; ++kf) {
      short8 bk[4];
      #pragma unroll
      for (int nf = 0; nf < 4; ++nf) bk[nf] = *(const short8*)&Ks[nf * 16 + lid][kf * 32 + grp * 8];
      #pragma unroll
      for (int mf = 0; mf < 2; ++mf)
        #pragma unroll
        for (int nf = 0; nf < 4; ++nf)
          sacc[mf][nf] = __builtin_amdgcn_mfma_f32_16x16x32_bf16(aq[mf][kf], bk[nf], sacc[mf][nf], 0, 0, 0);
    }
    #pragma unroll
    for (int mf = 0; mf < 2; ++mf) {
      #pragma unroll
      for (int nf = 0; nf < 4; ++nf) {
        #pragma unroll
        for (int r = 0; r < 4; ++r) {
          const float p = __expf(sacc[mf][nf][r] * scale) * rl[mf][r];
          const int qr = wv * 32 + mf * 16 + grp * 4 + r;
          const int kc = kt * 64 + nf * 16 + lid;
          attn[((size_t)bh * S_LEN + qt * 128 + qr) * S_LEN + kc] = p;
          QP[wv * 32 + (qr & 31)][nf * 16 + lid] = f2bf(p);
        }
      }
    }
    #pragma unroll
    for (int kf = 0; kf < 2; ++kf) {
      short8 ap[2], bvv[4];
      #pragma unroll
      for (int mf = 0; mf < 2; ++mf) ap[mf] = *(const short8*)&QP[wv * 32 + mf * 16 + lid][kf * 32 + grp * 8];
      #pragma unroll
      for (int nf = 0; nf < 4; ++nf) bvv[nf] = *(const short8*)&VT[nf * 16 + lid][kf * 32 + grp * 8];
      #pragma unroll
      for (int mf = 0; mf < 2; ++mf)
        #pragma unroll
        for (int nf = 0; nf < 4; ++nf)
          oacc[mf][nf] = __builtin_amdgcn_mfma_f32_16x16x32_bf16(ap[mf], bvv[nf], oacc[mf][nf], 0, 0, 0);
    }
  }

  const int b = bh >> 4, h = bh & 15;
  #pragma unroll
  for (int mf = 0; mf < 2; ++mf) {
    #pragma unroll
    for (int nf = 0; nf < 4; ++nf) {
      #pragma unroll
      for (int r = 0; r < 4; ++r) {
        const int s = qt * 128 + wv * 32 + mf * 16 + grp * 4 + r;
        const int d = nf * 16 + lid;
        xb[((size_t)b * S_LEN + s) * DM + h * DK + d] = f2bf(oacc[mf][nf][r]);
      }
    }
  }
}

extern "C" void kernel_launch(void* const* d_in, const int* in_sizes, int n_in,
                              void* d_out, int out_size, void* d_ws, size_t ws_size,
                              hipStream_t stream) {
  const float* q  = (const float*)d_in[0];
  const float* k  = (const float*)d_in[1];
  const float* v  = (const float*)d_in[2];
  const float* wq = (const float*)d_in[3];
  const float* bq = (const float*)d_in[4];
  const float* wk = (const float*)d_in[5];
  const float* bk = (const float*)d_in[6];
  const float* wv = (const float*)d_in[7];
  const float* bv = (const float*)d_in[8];
  const float* wo = (const float*)d_in[9];
  const float* bo = (const float*)d_in[10];

  float* out  = (float*)d_out;
  float* attn = out + (size_t)4 * S_LEN * DM;

  const size_t NTOK = (size_t)4 * S_LEN * DM;   // 8,388,608 elems
  const size_t NW   = (size_t)DM * DM;
  dim3 blk(256);

  if (ws_size >= 135000000ull) {
    short* qb  = (short*)d_ws;
    short* kb  = qb + NTOK;
    short* vb  = kb + NTOK;
    short* wqb = vb + NTOK;
    short* wkb = wqb + NW;
    short* wvb = wkb + NW;
    short* wob = wvb + NW;
    short* qhb = wob + NW;
    short* khb = qhb + NTOK;
    short* vtb = khb + NTOK;
    short* xb  = vtb + NTOK;

    cvt_bf16<<<dim3(4096, 3), blk, 0, stream>>>(q, k, v, (const float*)nullptr,
                                                qb, kb, vb, (short*)nullptr, (int)NTOK);
    cvt_bf16<<<dim3(512, 4), blk, 0, stream>>>(wq, wk, wv, wo, wqb, wkb, wvb, wob, (int)NW);

    proj3<<<dim3(64, 8, 3), blk, 0, stream>>>(qb, kb, vb, wqb, wkb, wvb, bq, bk, bv,
                                              qhb, khb, vtb);

    mha_attn9<<<dim3(2048), dim3(128), 0, stream>>>(qhb, khb, vtb, attn, xb);

    gemm_o<<<dim3(64, 8), blk, 0, stream>>>(xb, wob, bo, out);
  } else {
    short* qhb = (short*)d_ws;
    short* khb = qhb + NTOK;
    short* vhb = khb + NTOK;
    short* xb  = vhb + NTOK;

    mha_gemm<0><<<dim3(64, 8), blk, 0, stream>>>(q, (const short*)nullptr, wq, bq, qhb, (float*)nullptr);
    mha_gemm<0><<<dim3(64, 8), blk, 0, stream>>>(k, (const short*)nullptr, wk, bk, khb, (float*)nullptr);
    mha_gemm<0><<<dim3(64, 8), blk, 0, stream>>>(v, (const short*)nullptr, wv, bv, vhb, (float*)nullptr);
    mha_attn_old<<<dim3(16, 64), blk, 0, stream>>>(qhb, khb, vhb, attn, xb);
    mha_gemm<1><<<dim3(64, 8), blk, 0, stream>>>((const float*)nullptr, xb, wo, bo, (short*)nullptr, out);
  }
}

// Round 12
// 385.174 us; speedup vs baseline: 1.0661x; 1.0661x over previous
//
#include <hip/hip_runtime.h>
#include <math.h>

#define S_LEN 2048
#define DM 1024
#define NH 16
#define DK 64

typedef __attribute__((ext_vector_type(8))) short short8;
typedef __attribute__((ext_vector_type(4))) short short4v;
typedef __attribute__((ext_vector_type(4))) float f32x4;

// lgkm-only barrier: LDS handoff without draining global stores/prefetch (T4-lite)
#define LGKM_BARRIER() do { \
    asm volatile("s_waitcnt lgkmcnt(0)" ::: "memory"); \
    __builtin_amdgcn_s_barrier(); \
    __builtin_amdgcn_sched_barrier(0); \
  } while (0)

__device__ __forceinline__ short f2bf(float f) {
  unsigned u = __builtin_bit_cast(unsigned, f);
  u = (u + 0x7FFFu + ((u >> 16) & 1u)) >> 16;
  return (short)u;
}

__device__ __forceinline__ void gld_lds16(const short* g, short* l) {
  __builtin_amdgcn_global_load_lds(
      (const __attribute__((address_space(1))) unsigned int*)g,
      (__attribute__((address_space(3))) unsigned int*)l, 16, 0, 0);
}

// ---------------- f32 -> bf16 convert (blockIdx.y selects tensor) ----------------
__global__ __launch_bounds__(256) void cvt_bf16(
    const float* __restrict__ s0, const float* __restrict__ s1,
    const float* __restrict__ s2, const float* __restrict__ s3,
    short* __restrict__ d0, short* __restrict__ d1,
    short* __restrict__ d2, short* __restrict__ d3, int n)
{
  const float* s; short* d;
  switch (blockIdx.y) {
    case 0:  s = s0; d = d0; break;
    case 1:  s = s1; d = d1; break;
    case 2:  s = s2; d = d2; break;
    default: s = s3; d = d3; break;
  }
  const int i = (blockIdx.x * 256 + threadIdx.x) * 8;
  if (i < n) {
    const float4 v0 = *(const float4*)&s[i];
    const float4 v1 = *(const float4*)&s[i + 4];
    short8 r = { f2bf(v0.x), f2bf(v0.y), f2bf(v0.z), f2bf(v0.w),
                 f2bf(v1.x), f2bf(v1.y), f2bf(v1.z), f2bf(v1.w) };
    *(short8*)&d[i] = r;
  }
}

// ---------------- fused 3-way projection GEMM (m97 staging) ----------------------
// z=0: Q -> (B,H,S,DK); z=1: K -> (B,H,S,DK); z=2: V -> (B,H,DK,S) transposed
// (z==2 uses an LDS-transpose epilogue for coalesced V^T writes)
__global__ __launch_bounds__(256) void proj3(
    const short* __restrict__ qb, const short* __restrict__ kb, const short* __restrict__ vb,
    const short* __restrict__ wqb, const short* __restrict__ wkb, const short* __restrict__ wvb,
    const float* __restrict__ biq, const float* __restrict__ bik, const float* __restrict__ biv,
    short* __restrict__ qhb, short* __restrict__ khb, short* __restrict__ vtb)
{
  __shared__ short SM[17408];          // As(4096) + Bs(4096) during K-loop; Ct[128][136] in z==2 epilogue
  short* As = SM;
  short* Bs = SM + 4096;

  const int z = blockIdx.z;
  const short* A; const short* B; const float* bias; short* o;
  if (z == 0)      { A = qb; B = wqb; bias = biq; o = qhb; }
  else if (z == 1) { A = kb; B = wkb; bias = bik; o = khb; }
  else             { A = vb; B = wvb; bias = biv; o = vtb; }

  const int tid = threadIdx.x;
  const int lane = tid & 63;
  const int wv = tid >> 6;
  const int grp = lane >> 4, lid = lane & 15;
  const int wr = wv >> 1, wc = wv & 1;
  const int bm = blockIdx.x, bn = blockIdx.y;

  f32x4 acc[4][4] = {};

  const int idx0 = tid, idx1 = 256 + tid;
  const int r0 = idx0 >> 2, c0 = (idx0 & 3) * 8;
  const int r1 = idx1 >> 2, c1 = (idx1 & 3) * 8;
  const short* a0 = &A[(size_t)(bm * 128 + r0) * DM + c0];
  const short* a1 = &A[(size_t)(bm * 128 + r1) * DM + c1];
  const short* b0 = &B[(size_t)(bn * 128 + r0) * DM + c0];
  const short* b1 = &B[(size_t)(bn * 128 + r1) * DM + c1];

  for (int ks = 0; ks < 32; ++ks) {
    __syncthreads();
    gld_lds16(a0 + ks * 32, &As[idx0 * 8]);
    gld_lds16(a1 + ks * 32, &As[idx1 * 8]);
    gld_lds16(b0 + ks * 32, &Bs[idx0 * 8]);
    gld_lds16(b1 + ks * 32, &Bs[idx1 * 8]);
    __syncthreads();
    short8 a[4], b[4];
    #pragma unroll
    for (int m = 0; m < 4; ++m) a[m] = *(const short8*)&As[(wr * 64 + m * 16 + lid) * 32 + grp * 8];
    #pragma unroll
    for (int n = 0; n < 4; ++n) b[n] = *(const short8*)&Bs[(wc * 64 + n * 16 + lid) * 32 + grp * 8];
    #pragma unroll
    for (int m = 0; m < 4; ++m)
      #pragma unroll
      for (int n = 0; n < 4; ++n)
        acc[m][n] = __builtin_amdgcn_mfma_f32_16x16x32_bf16(a[m], b[n], acc[m][n], 0, 0, 0);
  }

  if (z < 2) {
    #pragma unroll
    for (int n = 0; n < 4; ++n) {
      const int ng = bn * 128 + wc * 64 + n * 16 + lid;
      const float bvs = bias[ng];
      const int h = ng >> 6, d = ng & 63;
      #pragma unroll
      for (int m = 0; m < 4; ++m) {
        const int mg = bm * 128 + wr * 64 + m * 16 + grp * 4;
        const int bb = mg >> 11, s = mg & 2047;
        #pragma unroll
        for (int r = 0; r < 4; ++r)
          o[(((size_t)bb * NH + h) * S_LEN + s + r) * DK + d] = f2bf(acc[m][n][r] + bvs);
      }
    }
  } else {
    // LDS transpose: C^T tile (rows = ng/dhead, cols = s), then coalesced writes
    __syncthreads();   // K-loop LDS reads done before overwriting with Ct
    #pragma unroll
    for (int n = 0; n < 4; ++n) {
      const int ngl = wc * 64 + n * 16 + lid;
      const float bvs = bias[bn * 128 + ngl];
      #pragma unroll
      for (int m = 0; m < 4; ++m) {
        const int sl = wr * 64 + m * 16 + grp * 4;
        short4v c4 = { f2bf(acc[m][n][0] + bvs), f2bf(acc[m][n][1] + bvs),
                       f2bf(acc[m][n][2] + bvs), f2bf(acc[m][n][3] + bvs) };
        *(short4v*)&SM[ngl * 136 + sl] = c4;
      }
    }
    __syncthreads();
    const int bb = bm >> 4, s0 = (bm & 15) * 128;
    #pragma unroll
    for (int i = 0; i < 8; ++i) {
      const int id = tid + 256 * i;         // 0..2047
      const int row = id >> 4;              // 0..127
      const int c8 = (id & 15) * 8;         // 0..120
      const short8 vv = *(const short8*)&SM[row * 136 + c8];
      *(short8*)&o[((size_t)bb * 1024 + bn * 128 + row) * S_LEN + s0 + c8] = vv;
    }
  }
}

// ---------------- O-projection: C = A @ B^T + bias -> f32 [M,DM] (NT out) --------
__global__ __launch_bounds__(256) void gemm_o(
    const short* __restrict__ A, const short* __restrict__ B,
    const float* __restrict__ bias, float* __restrict__ of)
{
  __shared__ short As[128 * 32];
  __shared__ short Bs[128 * 32];
  const int tid = threadIdx.x;
  const int lane = tid & 63;
  const int wv = tid >> 6;
  const int grp = lane >> 4, lid = lane & 15;
  const int wr = wv >> 1, wc = wv & 1;
  const int bm = blockIdx.x, bn = blockIdx.y;

  f32x4 acc[4][4] = {};

  const int idx0 = tid, idx1 = 256 + tid;
  const int r0 = idx0 >> 2, c0 = (idx0 & 3) * 8;
  const int r1 = idx1 >> 2, c1 = (idx1 & 3) * 8;
  const short* a0 = &A[(size_t)(bm * 128 + r0) * DM + c0];
  const short* a1 = &A[(size_t)(bm * 128 + r1) * DM + c1];
  const short* b0 = &B[(size_t)(bn * 128 + r0) * DM + c0];
  const short* b1 = &B[(size_t)(bn * 128 + r1) * DM + c1];

  for (int ks = 0; ks < 32; ++ks) {
    __syncthreads();
    gld_lds16(a0 + ks * 32, &As[idx0 * 8]);
    gld_lds16(a1 + ks * 32, &As[idx1 * 8]);
    gld_lds16(b0 + ks * 32, &Bs[idx0 * 8]);
    gld_lds16(b1 + ks * 32, &Bs[idx1 * 8]);
    __syncthreads();
    short8 a[4], b[4];
    #pragma unroll
    for (int m = 0; m < 4; ++m) a[m] = *(const short8*)&As[(wr * 64 + m * 16 + lid) * 32 + grp * 8];
    #pragma unroll
    for (int n = 0; n < 4; ++n) b[n] = *(const short8*)&Bs[(wc * 64 + n * 16 + lid) * 32 + grp * 8];
    #pragma unroll
    for (int m = 0; m < 4; ++m)
      #pragma unroll
      for (int n = 0; n < 4; ++n)
        acc[m][n] = __builtin_amdgcn_mfma_f32_16x16x32_bf16(a[m], b[n], acc[m][n], 0, 0, 0);
  }

  #pragma unroll
  for (int n = 0; n < 4; ++n) {
    const int ng = bn * 128 + wc * 64 + n * 16 + lid;
    const float bvs = bias[ng];
    #pragma unroll
    for (int m = 0; m < 4; ++m) {
      const int mg = bm * 128 + wr * 64 + m * 16 + grp * 4;
      #pragma unroll
      for (int r = 0; r < 4; ++r)
        __builtin_nontemporal_store(acc[m][n][r] + bvs, &of[(size_t)(mg + r) * DM + ng]);
    }
  }
}

// ---------------- fused attention v10 --------------------------------------------
// = v8 (R10, best known) + pass-1 reduction with 4 parallel accumulators
// (chain depth 16 -> 4). Everything else identical to v8.
__global__ __launch_bounds__(128) void mha_attn10(
    const short* __restrict__ qh, const short* __restrict__ kh, const short* __restrict__ vt,
    float* __restrict__ attn, short* __restrict__ xb)
{
  __shared__ short Kt[64][72];
  __shared__ short Vt[64][72];      // V^T tile: rows = d, cols = key
  __shared__ short Ps[2][32][72];   // per-wave normalized P (bf16); pass1: K dbuf

  const int tid = threadIdx.x;
  const int lane = tid & 63, wv = tid >> 6, grp = lane >> 4, lid = lane & 15;

  // XCD swizzle: all 32 q-tiles of one bh on one XCD (K+V^T = 512KB L2-resident)
  const int nid = blockIdx.x;               // 0..2047
  const int x = nid & 7, jj = nid >> 3;     // jj 0..255
  const int bh = x + 8 * (jj >> 5);         // 0..63
  const int qt = jj & 31;                   // 0..31 (64-row tiles)

  const size_t baseQ = (size_t)bh * S_LEN * DK;
  const size_t baseV = (size_t)bh * DK * S_LEN;
  const float scale2 = 0.18033688f;   // (1/8) * log2(e)

  const short* Qb = qh + baseQ;
  const short* Kb = kh + baseQ;
  const short* Vb = vt + baseV;

  // staging decomposition: 512 x 16B chunks per 64x64 bf16 tile, 4 per thread
  int tr[4], tc[4];
  #pragma unroll
  for (int i = 0; i < 4; ++i) {
    const int id = tid + 128 * i;
    tr[i] = id >> 3; tc[i] = (id & 7) * 8;
  }

  // Q fragments: direct global (16B/lane contiguous); used as mfma B-operand
  short8 aq[2][2];
  #pragma unroll
  for (int qb2 = 0; qb2 < 2; ++qb2)
    #pragma unroll
    for (int kf = 0; kf < 2; ++kf)
      aq[qb2][kf] = *(const short8*)&Qb[(size_t)(qt * 64 + wv * 32 + qb2 * 16 + lid) * DK + kf * 32 + grp * 8];

  float lsum[2][4] = {};   // 4 parallel accumulators per q-block (chain depth 4)

  // ---- pass 1: denominators; K double-buffered (Ps area), 1 barrier/step ----
  short8 kr[4];
  #pragma unroll
  for (int i = 0; i < 4; ++i) kr[i] = *(const short8*)&Kb[(size_t)tr[i] * DK + tc[i]];
  for (int kt = 0; kt < 32; ++kt) {
    short* buf = (kt & 1) ? &Ps[0][0][0] : &Kt[0][0];
    #pragma unroll
    for (int i = 0; i < 4; ++i) *(short8*)&buf[tr[i] * 72 + tc[i]] = kr[i];
    if (kt < 31) {
      #pragma unroll
      for (int i = 0; i < 4; ++i)
        kr[i] = *(const short8*)&Kb[(size_t)((kt + 1) * 64 + tr[i]) * DK + tc[i]];
    }
    LGKM_BARRIER();
    f32x4 sacc[4][2] = {};   // [key-block][q-block], C rows=key cols=q
    __builtin_amdgcn_s_setprio(1);
    #pragma unroll
    for (int kf = 0; kf < 2; ++kf) {
      short8 ak[4];
      #pragma unroll
      for (int kb2 = 0; kb2 < 4; ++kb2) ak[kb2] = *(const short8*)&buf[(kb2 * 16 + lid) * 72 + kf * 32 + grp * 8];
      #pragma unroll
      for (int kb2 = 0; kb2 < 4; ++kb2)
        #pragma unroll
        for (int qb2 = 0; qb2 < 2; ++qb2)
          sacc[kb2][qb2] = __builtin_amdgcn_mfma_f32_16x16x32_bf16(ak[kb2], aq[qb2][kf], sacc[kb2][qb2], 0, 0, 0);
    }
    __builtin_amdgcn_s_setprio(0);
    #pragma unroll
    for (int qb2 = 0; qb2 < 2; ++qb2)
      #pragma unroll
      for (int kb2 = 0; kb2 < 4; ++kb2) {
        float t0 = __builtin_amdgcn_exp2f(sacc[kb2][qb2][0] * scale2)
                 + __builtin_amdgcn_exp2f(sacc[kb2][qb2][1] * scale2);
        float t1 = __builtin_amdgcn_exp2f(sacc[kb2][qb2][2] * scale2)
                 + __builtin_amdgcn_exp2f(sacc[kb2][qb2][3] * scale2);
        lsum[qb2][kb2] += t0 + t1;   // independent chain per kb2
      }
  }

  float log2l[2];
  #pragma unroll
  for (int qb2 = 0; qb2 < 2; ++qb2) {
    float s = (lsum[qb2][0] + lsum[qb2][1]) + (lsum[qb2][2] + lsum[qb2][3]);
    s += __shfl_xor(s, 16);
    s += __shfl_xor(s, 32);
    log2l[qb2] = __log2f(s);
  }

  f32x4 oacc[2][4] = {};
  float* attnB = attn + ((size_t)bh * S_LEN + qt * 64 + wv * 32) * S_LEN;

  // ---- pass 2: recompute scores (swapped), P->Ps(b64 writes), PV, attn store ----
  short8 vr[4];
  #pragma unroll
  for (int i = 0; i < 4; ++i) {
    kr[i] = *(const short8*)&Kb[(size_t)tr[i] * DK + tc[i]];
    vr[i] = *(const short8*)&Vb[(size_t)tr[i] * S_LEN + tc[i]];
  }
  for (int kt = 0; kt < 32; ++kt) {
    LGKM_BARRIER();   // all waves done reading previous Kt/Vt/Ps (LDS only)
    #pragma unroll
    for (int i = 0; i < 4; ++i) {
      *(short8*)&Kt[tr[i]][tc[i]] = kr[i];
      *(short8*)&Vt[tr[i]][tc[i]] = vr[i];
    }
    if (kt < 31) {
      #pragma unroll
      for (int i = 0; i < 4; ++i) {
        kr[i] = *(const short8*)&Kb[(size_t)((kt + 1) * 64 + tr[i]) * DK + tc[i]];
        vr[i] = *(const short8*)&Vb[(size_t)tr[i] * S_LEN + (kt + 1) * 64 + tc[i]];
      }
    }
    LGKM_BARRIER();   // new Kt/Vt visible

    f32x4 sacc[4][2] = {};
    __builtin_amdgcn_s_setprio(1);
    #pragma unroll
    for (int kf = 0; kf < 2; ++kf) {
      short8 ak[4];
      #pragma unroll
      for (int kb2 = 0; kb2 < 4; ++kb2) ak[kb2] = *(const short8*)&Kt[kb2 * 16 + lid][kf * 32 + grp * 8];
      #pragma unroll
      for (int kb2 = 0; kb2 < 4; ++kb2)
        #pragma unroll
        for (int qb2 = 0; qb2 < 2; ++qb2)
          sacc[kb2][qb2] = __builtin_amdgcn_mfma_f32_16x16x32_bf16(ak[kb2], aq[qb2][kf], sacc[kb2][qb2], 0, 0, 0);
    }
    __builtin_amdgcn_s_setprio(0);

    // softmax -> Ps (normalization folded into exp2 arg); vector b64 writes
    #pragma unroll
    for (int qb2 = 0; qb2 < 2; ++qb2) {
      const float nl = -log2l[qb2];
      #pragma unroll
      for (int kb2 = 0; kb2 < 4; ++kb2) {
        short4v p4;
        #pragma unroll
        for (int r = 0; r < 4; ++r)
          p4[r] = f2bf(__builtin_amdgcn_exp2f(__builtin_fmaf(sacc[kb2][qb2][r], scale2, nl)));
        *(short4v*)&Ps[wv][qb2 * 16 + lid][kb2 * 16 + grp * 4] = p4;
      }
    }

    // PV from Ps + Vt (unchanged layout; intra-wave lgkm ordering)
    __builtin_amdgcn_s_setprio(1);
    #pragma unroll
    for (int kf = 0; kf < 2; ++kf) {
      short8 ap[2], bvv[4];
      #pragma unroll
      for (int mf = 0; mf < 2; ++mf) ap[mf] = *(const short8*)&Ps[wv][mf * 16 + lid][kf * 32 + grp * 8];
      #pragma unroll
      for (int nf = 0; nf < 4; ++nf) bvv[nf] = *(const short8*)&Vt[nf * 16 + lid][kf * 32 + grp * 8];
      #pragma unroll
      for (int mf = 0; mf < 2; ++mf)
        #pragma unroll
        for (int nf = 0; nf < 4; ++nf)
          oacc[mf][nf] = __builtin_amdgcn_mfma_f32_16x16x32_bf16(ap[mf], bvv[nf], oacc[mf][nf], 0, 0, 0);
    }
    __builtin_amdgcn_s_setprio(0);

    // attn f32 store sourced from Ps (bf16->f32 via bit ops), f32x4 NT stores
    #pragma unroll
    for (int i = 0; i < 8; ++i) {
      const int qrow = i * 4 + grp;
      const uint2 u = *(const uint2*)&Ps[wv][qrow][lid * 4];
      f32x4 f;
      f[0] = __builtin_bit_cast(float, u.x << 16);
      f[1] = __builtin_bit_cast(float, u.x & 0xffff0000u);
      f[2] = __builtin_bit_cast(float, u.y << 16);
      f[3] = __builtin_bit_cast(float, u.y & 0xffff0000u);
      __builtin_nontemporal_store(f, (f32x4*)&attnB[(size_t)qrow * S_LEN + kt * 64 + lid * 4]);
    }
  }

  // write attention output in (B,S,DM) bf16 layout for the O-projection
  const int b = bh >> 4, h = bh & 15;
  #pragma unroll
  for (int mf = 0; mf < 2; ++mf) {
    #pragma unroll
    for (int nf = 0; nf < 4; ++nf) {
      #pragma unroll
      for (int r = 0; r < 4; ++r) {
        const int s = qt * 64 + wv * 32 + mf * 16 + grp * 4 + r;
        const int d = nf * 16 + lid;
        xb[((size_t)b * S_LEN + s) * DM + h * DK + d] = f2bf(oacc[mf][nf][r]);
      }
    }
  }
}

// ================= fallback path kernels (small ws): round-2 structure ===========
template<int MODE>
__global__ __launch_bounds__(256) void mha_gemm(
    const float* __restrict__ Af, const short* __restrict__ Ab,
    const float* __restrict__ W, const float* __restrict__ bias,
    short* __restrict__ obf, float* __restrict__ of)
{
  __shared__ short As[128][40];
  __shared__ short Bs[128][40];
  const int tid = threadIdx.x;
  const int lane = tid & 63, wv = tid >> 6;
  const int grp = lane >> 4, lid = lane & 15;
  const int wr = wv >> 1, wc = wv & 1;
  const int bm = blockIdx.x, bn = blockIdx.y;

  f32x4 acc[4][4] = {};

  for (int ks = 0; ks < 32; ++ks) {
    __syncthreads();
    if (MODE == 0) {
      #pragma unroll
      for (int i = 0; i < 4; ++i) {
        const int c = tid + 256 * i;
        const int row = c >> 3, kc = c & 7;
        const float4 v = *(const float4*)&Af[(size_t)(bm * 128 + row) * DM + ks * 32 + kc * 4];
        short4v s4 = { f2bf(v.x), f2bf(v.y), f2bf(v.z), f2bf(v.w) };
        *(short4v*)&As[row][kc * 4] = s4;
      }
    } else {
      #pragma unroll
      for (int i = 0; i < 2; ++i) {
        const int c = tid + 256 * i;
        const int row = c >> 2, k8 = (c & 3) * 8;
        *(float4*)&As[row][k8] = *(const float4*)&Ab[(size_t)(bm * 128 + row) * DM + ks * 32 + k8];
      }
    }
    #pragma unroll
    for (int i = 0; i < 4; ++i) {
      const int c = tid + 256 * i;
      const int row = c >> 3, kc = c & 7;
      const float4 v = *(const float4*)&W[(size_t)(bn * 128 + row) * DM + ks * 32 + kc * 4];
      short4v s4 = { f2bf(v.x), f2bf(v.y), f2bf(v.z), f2bf(v.w) };
      *(short4v*)&Bs[row][kc * 4] = s4;
    }
    __syncthreads();
    short8 a[4], b[4];
    #pragma unroll
    for (int m = 0; m < 4; ++m) a[m] = *(const short8*)&As[wr * 64 + m * 16 + lid][grp * 8];
    #pragma unroll
    for (int n = 0; n < 4; ++n) b[n] = *(const short8*)&Bs[wc * 64 + n * 16 + lid][grp * 8];
    #pragma unroll
    for (int m = 0; m < 4; ++m)
      #pragma unroll
      for (int n = 0; n < 4; ++n)
        acc[m][n] = __builtin_amdgcn_mfma_f32_16x16x32_bf16(a[m], b[n], acc[m][n], 0, 0, 0);
  }

  #pragma unroll
  for (int n = 0; n < 4; ++n) {
    const int ng = bn * 128 + wc * 64 + n * 16 + lid;
    const float bvs = bias[ng];
    #pragma unroll
    for (int m = 0; m < 4; ++m) {
      const int mg = bm * 128 + wr * 64 + m * 16 + grp * 4;
      #pragma unroll
      for (int r = 0; r < 4; ++r) {
        const float val = acc[m][n][r] + bvs;
        const int mm = mg + r;
        if (MODE == 0) {
          const int bb = mm >> 11, s = mm & 2047, h = ng >> 6, d = ng & 63;
          obf[(((size_t)bb * NH + h) * S_LEN + s) * DK + d] = f2bf(val);
        } else {
          of[(size_t)mm * DM + ng] = val;
        }
      }
    }
  }
}

__global__ __launch_bounds__(256) void mha_attn_old(
    const short* __restrict__ qh, const short* __restrict__ kh, const short* __restrict__ vh,
    float* __restrict__ attn, short* __restrict__ xb)
{
  __shared__ short QP[128][72];
  __shared__ short Ks[64][72];
  __shared__ short VT[64][72];

  const int tid = threadIdx.x;
  const int lane = tid & 63, wv = tid >> 6, grp = lane >> 4, lid = lane & 15;
  const int qt = blockIdx.x, bh = blockIdx.y;
  const size_t base = (size_t)bh * S_LEN * DK;
  const float scale = 0.125f;

  #pragma unroll
  for (int i = 0; i < 4; ++i) {
    const int c = tid + 256 * i;
    const int row = c >> 3, k8 = (c & 7) * 8;
    *(float4*)&QP[row][k8] = *(const float4*)&qh[base + (size_t)(qt * 128 + row) * DK + k8];
  }
  __syncthreads();
  short8 aq[2][2];
  #pragma unroll
  for (int mf = 0; mf < 2; ++mf)
    #pragma unroll
    for (int kf = 0; kf < 2; ++kf)
      aq[mf][kf] = *(const short8*)&QP[wv * 32 + mf * 16 + lid][kf * 32 + grp * 8];

  float lsum[2][4] = {};

  for (int kt = 0; kt < 32; ++kt) {
    __syncthreads();
    #pragma unroll
    for (int i = 0; i < 2; ++i) {
      const int c = tid + 256 * i;
      const int row = c >> 3, k8 = (c & 7) * 8;
      *(float4*)&Ks[row][k8] = *(const float4*)&kh[base + (size_t)(kt * 64 + row) * DK + k8];
    }
    __syncthreads();
    f32x4 sacc[2][4] = {};
    #pragma unroll
    for (int kf = 0; kf < 2; ++kf) {
      short8 bk[4];
      #pragma unroll
      for (int nf = 0; nf < 4; ++nf) bk[nf] = *(const short8*)&Ks[nf * 16 + lid][kf * 32 + grp * 8];
      #pragma unroll
      for (int mf = 0; mf < 2; ++mf)
        #pragma unroll
        for (int nf = 0; nf < 4; ++nf)
          sacc[mf][nf] = __builtin_amdgcn_mfma_f32_16x16x32_bf16(aq[mf][kf], bk[nf], sacc[mf][nf], 0, 0, 0);
    }
    #pragma unroll
    for (int mf = 0; mf < 2; ++mf)
      #pragma unroll
      for (int r = 0; r < 4; ++r)
        #pragma unroll
        for (int nf = 0; nf < 4; ++nf)
          lsum[mf][r] += __expf(sacc[mf][nf][r] * scale);
  }

  float rl[2][4];
  #pragma unroll
  for (int mf = 0; mf < 2; ++mf)
    #pragma unroll
    for (int r = 0; r < 4; ++r) {
      float s = lsum[mf][r];
      #pragma unroll
      for (int off = 8; off >= 1; off >>= 1) s += __shfl_xor(s, off, 16);
      rl[mf][r] = 1.f / s;
    }

  f32x4 oacc[2][4] = {};

  for (int kt = 0; kt < 32; ++kt) {
    __syncthreads();
    #pragma unroll
    for (int i = 0; i < 2; ++i) {
      const int c = tid + 256 * i;
      const int row = c >> 3, k8 = (c & 7) * 8;
      *(float4*)&Ks[row][k8] = *(const float4*)&kh[base + (size_t)(kt * 64 + row) * DK + k8];
    }
    #pragma unroll
    for (int i = 0; i < 2; ++i) {
      const int key = tid & 63;
      const int d0 = ((tid >> 6) << 3) + i * 32;
      const float4 v = *(const float4*)&vh[base + (size_t)(kt * 64 + key) * DK + d0];
      const short8 sv = __builtin_bit_cast(short8, v);
      #pragma unroll
      for (int jj = 0; jj < 8; ++jj) VT[d0 + jj][key] = sv[jj];
    }
    __syncthreads();
    f32x4 sacc[2][4] = {};
    #pragma unroll
    for (int kf = 0; kf < 2; ++kf) {
      short8 bk[4];
      #pragma unroll
      for (int nf = 0; nf < 4; ++nf) bk[nf] = *(const short8*)&Ks[nf * 16 + lid][kf * 32 + grp * 8];
      #pragma unroll
      for (int mf = 0; mf < 2; ++mf)
        #pragma unroll
        for (int nf = 0; nf < 4; ++nf)
          sacc[mf][nf] = __builtin_amdgcn_mfma_f32_16x16x32_bf16(aq[mf][kf], bk[nf], sacc[mf][nf], 0, 0, 0);
    }
    #pragma unroll
    for (int mf = 0; mf < 2; ++mf) {
      #pragma unroll
      for (int nf = 0; nf < 4; ++nf) {
        #pragma unroll
        for (int r = 0; r < 4; ++r) {
          const float p = __expf(sacc[mf][nf][r] * scale) * rl[mf][r];
          const int qr = wv * 32 + mf * 16 + grp * 4 + r;
          const int kc = kt * 64 + nf * 16 + lid;
          attn[((size_t)bh * S_LEN + qt * 128 + qr) * S_LEN + kc] = p;
          QP[wv * 32 + (qr & 31)][nf * 16 + lid] = f2bf(p);
        }
      }
    }
    #pragma unroll
    for (int kf = 0; kf < 2; ++kf) {
      short8 ap[2], bvv[4];
      #pragma unroll
      for (int mf = 0; mf < 2; ++mf) ap[mf] = *(const short8*)&QP[wv * 32 + mf * 16 + lid][kf * 32 + grp * 8];
      #pragma unroll
      for (int nf = 0; nf < 4; ++nf) bvv[nf] = *(const short8*)&VT[nf * 16 + lid][kf * 32 + grp * 8];
      #pragma unroll
      for (int mf = 0; mf < 2; ++mf)
        #pragma unroll
        for (int nf = 0; nf < 4; ++nf)
          oacc[mf][nf] = __builtin_amdgcn_mfma_f32_16x16x32_bf16(ap[mf], bvv[nf], oacc[mf][nf], 0, 0, 0);
    }
  }

  const int b = bh >> 4, h = bh & 15;
  #pragma unroll
  for (int mf = 0; mf < 2; ++mf) {
    #pragma unroll
    for (int nf = 0; nf < 4; ++nf) {
      #pragma unroll
      for (int r = 0; r < 4; ++r) {
        const int s = qt * 128 + wv * 32 + mf * 16 + grp * 4 + r;
        const int d = nf * 16 + lid;
        xb[((size_t)b * S_LEN + s) * DM + h * DK + d] = f2bf(oacc[mf][nf][r]);
      }
    }
  }
}

extern "C" void kernel_launch(void* const* d_in, const int* in_sizes, int n_in,
                              void* d_out, int out_size, void* d_ws, size_t ws_size,
                              hipStream_t stream) {
  const float* q  = (const float*)d_in[0];
  const float* k  = (const float*)d_in[1];
  const float* v  = (const float*)d_in[2];
  const float* wq = (const float*)d_in[3];
  const float* bq = (const float*)d_in[4];
  const float* wk = (const float*)d_in[5];
  const float* bk = (const float*)d_in[6];
  const float* wv = (const float*)d_in[7];
  const float* bv = (const float*)d_in[8];
  const float* wo = (const float*)d_in[9];
  const float* bo = (const float*)d_in[10];

  float* out  = (float*)d_out;
  float* attn = out + (size_t)4 * S_LEN * DM;

  const size_t NTOK = (size_t)4 * S_LEN * DM;   // 8,388,608 elems
  const size_t NW   = (size_t)DM * DM;
  dim3 blk(256);

  if (ws_size >= 135000000ull) {
    short* qb  = (short*)d_ws;
    short* kb  = qb + NTOK;
    short* vb  = kb + NTOK;
    short* wqb = vb + NTOK;
    short* wkb = wqb + NW;
    short* wvb = wkb + NW;
    short* wob = wvb + NW;
    short* qhb = wob + NW;
    short* khb = qhb + NTOK;
    short* vtb = khb + NTOK;
    short* xb  = vtb + NTOK;

    cvt_bf16<<<dim3(4096, 3), blk, 0, stream>>>(q, k, v, (const float*)nullptr,
                                                qb, kb, vb, (short*)nullptr, (int)NTOK);
    cvt_bf16<<<dim3(512, 4), blk, 0, stream>>>(wq, wk, wv, wo, wqb, wkb, wvb, wob, (int)NW);

    proj3<<<dim3(64, 8, 3), blk, 0, stream>>>(qb, kb, vb, wqb, wkb, wvb, bq, bk, bv,
                                              qhb, khb, vtb);

    mha_attn10<<<dim3(2048), dim3(128), 0, stream>>>(qhb, khb, vtb, attn, xb);

    gemm_o<<<dim3(64, 8), blk, 0, stream>>>(xb, wob, bo, out);
  } else {
    short* qhb = (short*)d_ws;
    short* khb = qhb + NTOK;
    short* vhb = khb + NTOK;
    short* xb  = vhb + NTOK;

    mha_gemm<0><<<dim3(64, 8), blk, 0, stream>>>(q, (const short*)nullptr, wq, bq, qhb, (float*)nullptr);
    mha_gemm<0><<<dim3(64, 8), blk, 0, stream>>>(k, (const short*)nullptr, wk, bk, khb, (float*)nullptr);
    mha_gemm<0><<<dim3(64, 8), blk, 0, stream>>>(v, (const short*)nullptr, wv, bv, vhb, (float*)nullptr);
    mha_attn_old<<<dim3(16, 64), blk, 0, stream>>>(qhb, khb, vhb, attn, xb);
    mha_gemm<1><<<dim3(64, 8), blk, 0, stream>>>((const float*)nullptr, xb, wo, bo, (short*)nullptr, out);
  }
}